// Round 1
// 665.490 us; speedup vs baseline: 1.0122x; 1.0122x over previous
//
#include <hip/hip_runtime.h>
#include <float.h>
#include <math.h>

// Problem constants (fixed by the reference: N=8192, D=512, k+1=31).
#define NN 8192
#define DD 512
#define TOPK 31
#define CAPW 192          // per-wave candidate cap (typical cnt ~50)
#define DELTA 1e-4f       // sound |approx-exact| bound: lo*lo + requant ~5e-5
#define QEPS 4e-3f        // bf16-RNE storage error bound for |v| <= 2

// Strategy (R8):
//   Bit-exact value chain (absmax 0.0 since R3):
//     h = relu(f*W1)*W2 ; n = sqrtf(numpy-pairwise sum h*h) ; e = h/n
//     sim[i][j] = sequential-k fmaf chain over e_i*e_j ; stable top-31
//   Approx sim = bf16 MFMA: e = hi+lo, acc = hi*hi + lo*hi + hi*lo (one
//   merged K-loop, 4 tiles staged per k-block). Upper-triangle blocks only.
//   NEW (R8): sim is stored as bf16 packed into the SECOND 16KB of each
//   output f32 row (row i's scratch lives inside row i's own 32KB span ->
//   no cross-block hazard, no extra workspace; halves sim write + topk read).
//   topk: T = 31st tile-max via O(64) independent-shuffle rank-select;
//   one bf16 row pass collects candidates >= T - 2*DELTA - QEPS; exact
//   chains re-rank; write full f32 row. CAPW=192 -> 19.4KB LDS -> 8 blk/CU.

typedef __attribute__((ext_vector_type(8))) short short8;
typedef __attribute__((ext_vector_type(4))) float f32x4;

__device__ __forceinline__ float h_elem(const float* __restrict__ f,
                                        const float* __restrict__ W1,
                                        const float* __restrict__ W2, int k) {
  float x = f[k] * W1[k];
  x = fmaxf(x, 0.0f);
  return x * W2[k];
}

__device__ __forceinline__ unsigned short f2bf_rne(float x) {
  unsigned u = __float_as_uint(x);
  unsigned r = (u >> 16) & 1u;
  u += 0x7fffu + r;
  return (unsigned short)(u >> 16);
}
__device__ __forceinline__ float bf2f(unsigned short h) {
  return __uint_as_float(((unsigned)h) << 16);
}
__device__ __forceinline__ unsigned ordmap(float x) {
  unsigned u = __float_as_uint(x);
  return (u & 0x80000000u) ? ~u : (u | 0x80000000u);
}
__device__ __forceinline__ float ordunmap(unsigned u) {
  return __uint_as_float((u & 0x80000000u) ? (u & 0x7fffffffu) : ~u);
}

// bf16 scratch image of sim row i: second half of output row i's 32KB span.
__device__ __forceinline__ unsigned short* bfrow(float* C, int row) {
  return (unsigned short*)C + (size_t)row * (2 * NN) + NN;
}

// ---------------------------------------------------------------------------
// Kernel A: fused norm (numpy pairwise association, bit-exact) + e = h/n,
// bf16 hi/lo split, flag zeroing. One wave per row.
// ---------------------------------------------------------------------------
__global__ __launch_bounds__(256) void emb_kernel(
    const float* __restrict__ f, const float* __restrict__ W1,
    const float* __restrict__ W2, float* __restrict__ e32,
    unsigned short* __restrict__ Ehi, unsigned short* __restrict__ Elo,
    int* __restrict__ flags) {
  const int lane = threadIdx.x & 63;
  const int row = blockIdx.x * 4 + (threadIdx.x >> 6);
  const float* fr = f + (size_t)row * DD;
  const int b = lane >> 4, L = lane & 15;
  if (lane == 0) flags[row] = 0;

  float s[8];
#pragma unroll
  for (int j = 0; j < 8; ++j) {
    float h = h_elem(fr, W1, W2, b * 128 + 16 * j + L);
    s[j] = h * h;
  }
  float v = ((s[0] + s[1]) + (s[2] + s[3])) + ((s[4] + s[5]) + (s[6] + s[7]));
  float t = v + __shfl_xor(v, 8);
  t = t + __shfl_xor(t, 4);
  t = t + __shfl_xor(t, 2);
  float nb = t + __shfl_xor(t, 1);
  float x = nb + __shfl_xor(nb, 16);
  float norm2 = x + __shfl_xor(x, 32);
  const float n = fmaxf(sqrtf(norm2), 1e-12f);

  float* er = e32 + (size_t)row * DD;
  unsigned short* hr = Ehi + (size_t)row * DD;
  unsigned short* lr = Elo + (size_t)row * DD;
#pragma unroll
  for (int m = 0; m < 8; ++m) {
    int k = m * 64 + lane;
    float e = h_elem(fr, W1, W2, k) / n;
    er[k] = e;
    unsigned short hb = f2bf_rne(e);
    hr[k] = hb;
    lr[k] = f2bf_rne(e - bf2f(hb));
  }
}

// ---------------------------------------------------------------------------
// Kernel B: merged 3-term bf16 MFMA sim, upper-triangle 128x128 tiles.
// One K-loop (BK=32) staging Ahi/Alo/Bhi/Blo; 48 MFMAs per barrier pair.
// Epilogue: bf16 tile write into per-row scratch halves + per-row tile-max TM
// + (bx>by) transposed mirror tile via LDS strips + transposed TM.
// LDS tiles: stride 40 shorts -> frag read banks (20r+4q)%32, 2-way max.
// ---------------------------------------------------------------------------
#define TSTR 40                     // LDS tile row stride in shorts
#define OF_AH 0
#define OF_AL (128 * TSTR)
#define OF_BH (2 * 128 * TSTR)
#define OF_BL (3 * 128 * TSTR)

__global__ __launch_bounds__(256) void sim_mfma(
    const unsigned short* __restrict__ Ehi,
    const unsigned short* __restrict__ Elo, float* __restrict__ C,
    float* __restrict__ TM) {
  const int bx = blockIdx.x, by = blockIdx.y;
  if (bx < by) return;

  __shared__ __align__(16) char smem[4 * 128 * TSTR * 2];  // 40960 B
  unsigned short* S = (unsigned short*)smem;
  float(*Tt)[132] = (float(*)[132])smem;  // epilogue alias (33792 B)
  __shared__ float rmx[128][2];
  __shared__ float cmx[128][2];

  const int t = threadIdx.x;
  const int lane = t & 63, w = t >> 6;
  const int wr = w >> 1, wc = w & 1;
  const int quad = lane >> 4, l16 = lane & 15;
  const int i0 = by * 128, j0 = bx * 128;

  f32x4 acc[4][4];
#pragma unroll
  for (int a = 0; a < 4; ++a)
#pragma unroll
    for (int b = 0; b < 4; ++b) acc[a][b] = (f32x4){0.f, 0.f, 0.f, 0.f};

  const int sr = t >> 1;          // staging row 0..127
  const int c0 = (t & 1) * 16;    // staging k-offset in shorts: 0 or 16
  const size_t ga = (size_t)(i0 + sr) * DD;
  const size_t gb = (size_t)(j0 + sr) * DD;

  for (int kk = 0; kk < DD; kk += 32) {
    __syncthreads();
    uint4 ah0 = *(const uint4*)&Ehi[ga + kk + c0];
    uint4 ah1 = *(const uint4*)&Ehi[ga + kk + c0 + 8];
    uint4 al0 = *(const uint4*)&Elo[ga + kk + c0];
    uint4 al1 = *(const uint4*)&Elo[ga + kk + c0 + 8];
    uint4 bh0 = *(const uint4*)&Ehi[gb + kk + c0];
    uint4 bh1 = *(const uint4*)&Ehi[gb + kk + c0 + 8];
    uint4 bl0 = *(const uint4*)&Elo[gb + kk + c0];
    uint4 bl1 = *(const uint4*)&Elo[gb + kk + c0 + 8];
    *(uint4*)&S[OF_AH + sr * TSTR + c0] = ah0;
    *(uint4*)&S[OF_AH + sr * TSTR + c0 + 8] = ah1;
    *(uint4*)&S[OF_AL + sr * TSTR + c0] = al0;
    *(uint4*)&S[OF_AL + sr * TSTR + c0 + 8] = al1;
    *(uint4*)&S[OF_BH + sr * TSTR + c0] = bh0;
    *(uint4*)&S[OF_BH + sr * TSTR + c0 + 8] = bh1;
    *(uint4*)&S[OF_BL + sr * TSTR + c0] = bl0;
    *(uint4*)&S[OF_BL + sr * TSTR + c0 + 8] = bl1;
    __syncthreads();

    short8 ah[4], al[4], bh[4];
#pragma unroll
    for (int mt = 0; mt < 4; ++mt) {
      int rr = (wr * 64 + mt * 16 + l16) * TSTR + quad * 8;
      ah[mt] = *(const short8*)&S[OF_AH + rr];
      al[mt] = *(const short8*)&S[OF_AL + rr];
    }
#pragma unroll
    for (int nt = 0; nt < 4; ++nt)
      bh[nt] = *(const short8*)&S[OF_BH + (wc * 64 + nt * 16 + l16) * TSTR + quad * 8];
#pragma unroll
    for (int mt = 0; mt < 4; ++mt)
#pragma unroll
      for (int nt = 0; nt < 4; ++nt)
        acc[mt][nt] = __builtin_amdgcn_mfma_f32_16x16x32_bf16(ah[mt], bh[nt], acc[mt][nt], 0, 0, 0);
#pragma unroll
    for (int mt = 0; mt < 4; ++mt)
#pragma unroll
      for (int nt = 0; nt < 4; ++nt)
        acc[mt][nt] = __builtin_amdgcn_mfma_f32_16x16x32_bf16(al[mt], bh[nt], acc[mt][nt], 0, 0, 0);
    short8 bl[4];
#pragma unroll
    for (int nt = 0; nt < 4; ++nt)
      bl[nt] = *(const short8*)&S[OF_BL + (wc * 64 + nt * 16 + l16) * TSTR + quad * 8];
#pragma unroll
    for (int mt = 0; mt < 4; ++mt)
#pragma unroll
      for (int nt = 0; nt < 4; ++nt)
        acc[mt][nt] = __builtin_amdgcn_mfma_f32_16x16x32_bf16(ah[mt], bl[nt], acc[mt][nt], 0, 0, 0);
  }

  // --- normal tile write: bf16 into per-row scratch (col = l16, row = quad*4+r)
#pragma unroll
  for (int mt = 0; mt < 4; ++mt)
#pragma unroll
    for (int r = 0; r < 4; ++r) {
      int row = i0 + wr * 64 + mt * 16 + quad * 4 + r;
      unsigned short* Br = bfrow(C, row) + j0 + wc * 64;
#pragma unroll
      for (int nt = 0; nt < 4; ++nt) Br[nt * 16 + l16] = f2bf_rne(acc[mt][nt][r]);
    }

  // --- per-row tile-max (rows of this tile) ---
#pragma unroll
  for (int mt = 0; mt < 4; ++mt)
#pragma unroll
    for (int r = 0; r < 4; ++r) {
      float m = fmaxf(fmaxf(acc[mt][0][r], acc[mt][1][r]),
                      fmaxf(acc[mt][2][r], acc[mt][3][r]));
      m = fmaxf(m, __shfl_xor(m, 1));
      m = fmaxf(m, __shfl_xor(m, 2));
      m = fmaxf(m, __shfl_xor(m, 4));
      m = fmaxf(m, __shfl_xor(m, 8));
      if (l16 == 0) rmx[wr * 64 + mt * 16 + quad * 4 + r][wc] = m;
    }
  // --- per-col tile-max (rows of the mirrored tile), only if off-diagonal ---
  if (bx > by) {
#pragma unroll
    for (int nt = 0; nt < 4; ++nt) {
      float c = -FLT_MAX;
#pragma unroll
      for (int mt = 0; mt < 4; ++mt)
#pragma unroll
        for (int r = 0; r < 4; ++r) c = fmaxf(c, acc[mt][nt][r]);
      c = fmaxf(c, __shfl_xor(c, 16));
      c = fmaxf(c, __shfl_xor(c, 32));
      if (quad == 0) cmx[wc * 64 + nt * 16 + l16][wr] = c;
    }
  }
  __syncthreads();
  if (t < 128) TM[(size_t)(i0 + t) * 64 + bx] = fmaxf(rmx[t][0], rmx[t][1]);
  if (bx > by) {
    if (t < 128) TM[(size_t)(j0 + t) * 64 + by] = fmaxf(cmx[t][0], cmx[t][1]);
    // --- transposed mirror write via LDS strips (Tt aliases S), bf16 out ---
    for (int s = 0; s < 2; ++s) {
      __syncthreads();
      if (wc == s) {
#pragma unroll
        for (int mt = 0; mt < 4; ++mt)
#pragma unroll
          for (int nt = 0; nt < 4; ++nt)
#pragma unroll
            for (int r = 0; r < 4; ++r)
              Tt[nt * 16 + l16][wr * 64 + mt * 16 + quad * 4 + r] = acc[mt][nt][r];
      }
      __syncthreads();
#pragma unroll
      for (int q = 0; q < 8; ++q) {
        int fi = q * 256 + t;
        int rr = fi >> 5;
        int cc4 = (fi & 31) * 4;
        ushort4 v;
        v.x = f2bf_rne(Tt[rr][cc4]);
        v.y = f2bf_rne(Tt[rr][cc4 + 1]);
        v.z = f2bf_rne(Tt[rr][cc4 + 2]);
        v.w = f2bf_rne(Tt[rr][cc4 + 3]);
        *(ushort4*)(bfrow(C, j0 + s * 64 + rr) + i0 + cc4) = v;
      }
    }
  }
}

// ---------------------------------------------------------------------------
// Kernel C: one WAVE per row. T = 31st largest tile-max via O(64) rank-select
// (63 independent shuffles, identical tie-break to sequential argmax).
// Single pass over the bf16 row scratch collects cands >= T - 2*DELTA - QEPS;
// exact fmaf chains re-rank; write zeros + relu(exact). Overflow -> flag.
// LDS ~19.4KB -> 8 blocks/CU -> full 32-wave occupancy.
// ---------------------------------------------------------------------------
__global__ __launch_bounds__(256) void topk_kernel(float* __restrict__ C,
                                                   const float* __restrict__ e32,
                                                   const float* __restrict__ TM,
                                                   int* __restrict__ flags) {
  const int w = threadIdx.x >> 6;
  const int lane = threadIdx.x & 63;
  const int row = blockIdx.x * 4 + w;

  __shared__ float er[4][DD];
  __shared__ int cidx[4][CAPW];
  __shared__ float cval[4][CAPW];
  __shared__ unsigned long long bmap[4][NN / 64];
  __shared__ int wcnt[4];
  __shared__ int kidx[4][TOPK];
  __shared__ float kval[4][TOPK];

  {
    const float4* e4 = (const float4*)(e32 + (size_t)row * DD);
    float4* er4 = (float4*)er[w];
    er4[lane] = e4[lane];
    er4[64 + lane] = e4[64 + lane];
  }
  if (lane == 0) wcnt[w] = 0;
#pragma unroll
  for (int q = 0; q < 2; ++q) bmap[w][q * 64 + lane] = 0ull;

  // T = 31st largest of 64 tile maxima: rank-select with independent shuffles.
  // rank = #{j : key_j > key_i, tie -> smaller lane}; lane with rank==30 has T.
  float mv = TM[(size_t)row * 64 + lane];
  unsigned key = ordmap(mv);
  int rank = 0;
#pragma unroll
  for (int off = 1; off < 64; ++off) {
    int ol = (lane + off) & 63;
    unsigned ok = __shfl(key, ol);
    rank += (ok > key || (ok == key && ol < lane)) ? 1 : 0;
  }
  unsigned long long bmsk = __ballot(rank == TOPK - 1);
  float T = __shfl(mv, __ffsll((unsigned long long)bmsk) - 1);

  // single row pass over bf16 scratch: collect candidates
  const float Tc = T - 2.0f * DELTA - QEPS;
  const unsigned short* Brow = (const unsigned short*)C + (size_t)row * (2 * NN) + NN;
  const uint4* Br4 = (const uint4*)Brow;
  for (int it = 0; it < NN / 512; ++it) {
    uint4 v = Br4[it * 64 + lane];
    int j = (it * 64 + lane) * 8;
    unsigned wv[4] = {v.x, v.y, v.z, v.w};
#pragma unroll
    for (int c = 0; c < 4; ++c) {
      float f0 = __uint_as_float(wv[c] << 16);
      float f1 = __uint_as_float(wv[c] & 0xffff0000u);
      if (f0 >= Tc) { int p = atomicAdd(&wcnt[w], 1); if (p < CAPW) cidx[w][p] = j + 2 * c; }
      if (f1 >= Tc) { int p = atomicAdd(&wcnt[w], 1); if (p < CAPW) cidx[w][p] = j + 2 * c + 1; }
    }
  }
  const int cnt = wcnt[w];

  if (cnt > CAPW) {
    if (lane == 0) flags[row] = 1;
    return;
  }

  // exact sequential-k fmaf chains (bit-identical to the verified chain)
  for (int c = lane; c < cnt; c += 64) {
    const float4* ej4 = (const float4*)(e32 + (size_t)cidx[w][c] * DD);
    float a = 0.f;
    for (int k4 = 0; k4 < DD / 4; ++k4) {
      float4 vv = ej4[k4];
      const float* e = &er[w][k4 * 4];
      a = fmaf(e[0], vv.x, a);
      a = fmaf(e[1], vv.y, a);
      a = fmaf(e[2], vv.z, a);
      a = fmaf(e[3], vv.w, a);
    }
    cval[w][c] = a;
  }

  // stable top-31 by (exact desc, idx asc)
  for (int c = lane; c < cnt; c += 64) {
    float v = cval[w][c];
    int idx = cidx[w][c];
    int rnk = 0;
    for (int c2 = 0; c2 < cnt; ++c2) {
      float v2 = cval[w][c2];
      if (v2 > v || (v2 == v && cidx[w][c2] < idx)) ++rnk;
    }
    if (rnk < TOPK) {
      kidx[w][rnk] = idx;
      kval[w][rnk] = fmaxf(v, 0.0f);
      atomicOr(&bmap[w][idx >> 6], 1ull << (idx & 63));
    }
  }

  // write the output row (0 or kept value)
  float* Crow = C + (size_t)row * NN;
  float4* Cw4 = (float4*)Crow;
  for (int it = 0; it < 32; ++it) {
    int j4 = (it * 64 + lane) * 4;
    float4 o = make_float4(0.f, 0.f, 0.f, 0.f);
    unsigned long long word = bmap[w][j4 >> 6];
    unsigned nib = (unsigned)((word >> (j4 & 63)) & 0xFull);
    if (nib) {
#pragma unroll
      for (int c = 0; c < 4; ++c)
        if ((nib >> c) & 1u) {
          int j = j4 + c;
          float val = 0.f;
          for (int s = 0; s < TOPK; ++s)
            if (kidx[w][s] == j) val = kval[w][s];
          ((float*)&o)[c] = val;
        }
    }
    Cw4[it * 64 + lane] = o;
  }
}

// ---------------------------------------------------------------------------
// Kernel D: exact cleanup for flagged rows (statistically never executes).
// ---------------------------------------------------------------------------
__global__ __launch_bounds__(256) void cleanup_kernel(
    float* __restrict__ C, const float* __restrict__ e32,
    const int* __restrict__ flags) {
  const int row = blockIdx.x;
  if (flags[row] == 0) return;
  const int tid = threadIdx.x;
  const int lane = tid & 63, wid = tid >> 6;

  __shared__ float sv[NN];
  __shared__ float er[DD];
  __shared__ unsigned long long wred[4];
  __shared__ int kidx[TOPK];
  __shared__ float kval[TOPK];

  {
    const float4* e4 = (const float4*)(e32 + (size_t)row * DD);
    if (tid < DD / 4) ((float4*)er)[tid] = e4[tid];
  }
  __syncthreads();

  for (int m = 0; m < NN / 256; ++m) {
    int j = m * 256 + tid;
    const float* ej = e32 + (size_t)j * DD;
    float a = 0.f;
    for (int k = 0; k < DD; k += 4) {
      float4 v = *(const float4*)&ej[k];
      a = fmaf(er[k], v.x, a);
      a = fmaf(er[k + 1], v.y, a);
      a = fmaf(er[k + 2], v.z, a);
      a = fmaf(er[k + 3], v.w, a);
    }
    sv[j] = a;
  }
  __syncthreads();

  for (int it = 0; it < TOPK; ++it) {
    float bv = -FLT_MAX;
    int bi = 0;
    for (int j = tid; j < NN; j += 256) {
      float v = sv[j];
      if (v > bv) { bv = v; bi = j; }
    }
    unsigned long long key =
        ((unsigned long long)ordmap(bv) << 32) | (unsigned)(NN - 1 - bi);
#pragma unroll
    for (int off = 32; off; off >>= 1) {
      unsigned long long o = __shfl_xor(key, off);
      if (o > key) key = o;
    }
    if (lane == 0) wred[wid] = key;
    __syncthreads();
    if (tid == 0) {
      unsigned long long k0 = wred[0];
      if (wred[1] > k0) k0 = wred[1];
      if (wred[2] > k0) k0 = wred[2];
      if (wred[3] > k0) k0 = wred[3];
      int idx = (NN - 1) - (int)(k0 & 0xFFFFFFFFu);
      kidx[it] = idx;
      kval[it] = sv[idx];
      sv[idx] = -FLT_MAX;
    }
    __syncthreads();
  }

  float4 z4 = make_float4(0.f, 0.f, 0.f, 0.f);
  float4* sv4 = (float4*)sv;
  for (int i = tid; i < NN / 4; i += 256) sv4[i] = z4;
  __syncthreads();
  if (tid < TOPK) sv[kidx[tid]] = fmaxf(kval[tid], 0.0f);
  __syncthreads();
  float4* Cw4 = (float4*)(C + (size_t)row * NN);
  for (int i = tid; i < NN / 4; i += 256) Cw4[i] = sv4[i];
}

// ---------------------------------------------------------------------------
extern "C" void kernel_launch(void* const* d_in, const int* in_sizes, int n_in,
                              void* d_out, int out_size, void* d_ws,
                              size_t ws_size, hipStream_t stream) {
  const float* f = (const float*)d_in[0];
  const float* W1 = (const float*)d_in[1];
  const float* W2 = (const float*)d_in[2];
  float* out = (float*)d_out;
  char* ws = (char*)d_ws;
  float* e32 = (float*)ws;                                     // 16 MiB
  unsigned short* Ehi = (unsigned short*)(ws + (size_t)NN * DD * 4);   // 8 MiB
  unsigned short* Elo = (unsigned short*)(ws + (size_t)NN * DD * 6);   // 8 MiB
  float* TM = (float*)(ws + (size_t)NN * DD * 8);              // 2 MiB
  int* flags = (int*)(ws + (size_t)NN * DD * 8 + (size_t)NN * 64 * 4);  // 32 KB

  emb_kernel<<<NN / 4, 256, 0, stream>>>(f, W1, W2, e32, Ehi, Elo, flags);
  dim3 g2(NN / 128, NN / 128);
  sim_mfma<<<g2, 256, 0, stream>>>(Ehi, Elo, out, TM);
  topk_kernel<<<NN / 4, 256, 0, stream>>>(out, e32, TM, flags);
  cleanup_kernel<<<NN, 256, 0, stream>>>(out, e32, flags);
}

// Round 2
// 616.032 us; speedup vs baseline: 1.0934x; 1.0803x over previous
//
#include <hip/hip_runtime.h>
#include <float.h>
#include <math.h>

// Problem constants (fixed by the reference: N=8192, D=512, k+1=31).
#define NN 8192
#define DD 512
#define TOPK 31
#define CAPW 192          // per-wave candidate cap (typical cnt ~50)
#define DELTA 1e-4f       // sound |approx-exact| bound: lo*lo + requant ~5e-5

// Strategy (R9):
//   Bit-exact value chain (absmax 0.0 since R3):
//     h = relu(f*W1)*W2 ; n = sqrtf(numpy-pairwise sum h*h) ; e = h/n
//     sim[i][j] = sequential-k fmaf chain over e_i*e_j ; stable top-31
//   Approx sim = bf16 MFMA: e = hi+lo, acc = hi*hi + lo*hi + hi*lo (one
//   merged K-loop, 4 tiles staged per k-block). Upper-triangle blocks only.
//   sim scratch stored as ROUND-UP bf16 in the SECOND 16KB of each output
//   f32 row (stored >= approx -> threshold needs no quantization widening).
//   NEW (R9): topk split into collect (latency-bound: T rank-select, scan,
//   exact chains, stable rank -> KV[row][31] pairs) and write_kernel
//   (BW-bound: streaming zero-fill + 31-value scatter per row).

typedef __attribute__((ext_vector_type(8))) short short8;
typedef __attribute__((ext_vector_type(4))) float f32x4;

__device__ __forceinline__ float h_elem(const float* __restrict__ f,
                                        const float* __restrict__ W1,
                                        const float* __restrict__ W2, int k) {
  float x = f[k] * W1[k];
  x = fmaxf(x, 0.0f);
  return x * W2[k];
}

__device__ __forceinline__ unsigned short f2bf_rne(float x) {
  unsigned u = __float_as_uint(x);
  unsigned r = (u >> 16) & 1u;
  u += 0x7fffu + r;
  return (unsigned short)(u >> 16);
}
// Round toward +inf: guarantees bf16(x) >= x. (pos: ceil; neg: trunc->up)
__device__ __forceinline__ unsigned short f2bf_ru(float x) {
  unsigned u = __float_as_uint(x);
  if (!(u >> 31)) u += 0xffffu;
  return (unsigned short)(u >> 16);
}
__device__ __forceinline__ float bf2f(unsigned short h) {
  return __uint_as_float(((unsigned)h) << 16);
}
__device__ __forceinline__ unsigned ordmap(float x) {
  unsigned u = __float_as_uint(x);
  return (u & 0x80000000u) ? ~u : (u | 0x80000000u);
}
__device__ __forceinline__ float ordunmap(unsigned u) {
  return __uint_as_float((u & 0x80000000u) ? (u & 0x7fffffffu) : ~u);
}

// bf16 scratch image of sim row i: second half of output row i's 32KB span.
__device__ __forceinline__ unsigned short* bfrow(float* C, int row) {
  return (unsigned short*)C + (size_t)row * (2 * NN) + NN;
}

// ---------------------------------------------------------------------------
// Kernel A: fused norm (numpy pairwise association, bit-exact) + e = h/n,
// bf16 hi/lo split (RNE), flag zeroing. One wave per row.
// ---------------------------------------------------------------------------
__global__ __launch_bounds__(256) void emb_kernel(
    const float* __restrict__ f, const float* __restrict__ W1,
    const float* __restrict__ W2, float* __restrict__ e32,
    unsigned short* __restrict__ Ehi, unsigned short* __restrict__ Elo,
    int* __restrict__ flags) {
  const int lane = threadIdx.x & 63;
  const int row = blockIdx.x * 4 + (threadIdx.x >> 6);
  const float* fr = f + (size_t)row * DD;
  const int b = lane >> 4, L = lane & 15;
  if (lane == 0) flags[row] = 0;

  float s[8];
#pragma unroll
  for (int j = 0; j < 8; ++j) {
    float h = h_elem(fr, W1, W2, b * 128 + 16 * j + L);
    s[j] = h * h;
  }
  float v = ((s[0] + s[1]) + (s[2] + s[3])) + ((s[4] + s[5]) + (s[6] + s[7]));
  float t = v + __shfl_xor(v, 8);
  t = t + __shfl_xor(t, 4);
  t = t + __shfl_xor(t, 2);
  float nb = t + __shfl_xor(t, 1);
  float x = nb + __shfl_xor(nb, 16);
  float norm2 = x + __shfl_xor(x, 32);
  const float n = fmaxf(sqrtf(norm2), 1e-12f);

  float* er = e32 + (size_t)row * DD;
  unsigned short* hr = Ehi + (size_t)row * DD;
  unsigned short* lr = Elo + (size_t)row * DD;
#pragma unroll
  for (int m = 0; m < 8; ++m) {
    int k = m * 64 + lane;
    float e = h_elem(fr, W1, W2, k) / n;
    er[k] = e;
    unsigned short hb = f2bf_rne(e);
    hr[k] = hb;
    lr[k] = f2bf_rne(e - bf2f(hb));
  }
}

// ---------------------------------------------------------------------------
// Kernel B: merged 3-term bf16 MFMA sim, upper-triangle 128x128 tiles.
// One K-loop (BK=32) staging Ahi/Alo/Bhi/Blo; 48 MFMAs per barrier pair.
// Epilogue: round-up bf16 tile write into per-row scratch halves + per-row
// tile-max TM + (bx>by) transposed mirror tile via LDS strips + transposed TM.
// LDS tiles: stride 40 shorts -> frag read banks (20r+4q)%32, 2-way max.
// ---------------------------------------------------------------------------
#define TSTR 40                     // LDS tile row stride in shorts
#define OF_AH 0
#define OF_AL (128 * TSTR)
#define OF_BH (2 * 128 * TSTR)
#define OF_BL (3 * 128 * TSTR)

__global__ __launch_bounds__(256) void sim_mfma(
    const unsigned short* __restrict__ Ehi,
    const unsigned short* __restrict__ Elo, float* __restrict__ C,
    float* __restrict__ TM) {
  const int bx = blockIdx.x, by = blockIdx.y;
  if (bx < by) return;

  __shared__ __align__(16) char smem[4 * 128 * TSTR * 2];  // 40960 B
  unsigned short* S = (unsigned short*)smem;
  float(*Tt)[132] = (float(*)[132])smem;  // epilogue alias (33792 B)
  __shared__ float rmx[128][2];
  __shared__ float cmx[128][2];

  const int t = threadIdx.x;
  const int lane = t & 63, w = t >> 6;
  const int wr = w >> 1, wc = w & 1;
  const int quad = lane >> 4, l16 = lane & 15;
  const int i0 = by * 128, j0 = bx * 128;

  f32x4 acc[4][4];
#pragma unroll
  for (int a = 0; a < 4; ++a)
#pragma unroll
    for (int b = 0; b < 4; ++b) acc[a][b] = (f32x4){0.f, 0.f, 0.f, 0.f};

  const int sr = t >> 1;          // staging row 0..127
  const int c0 = (t & 1) * 16;    // staging k-offset in shorts: 0 or 16
  const size_t ga = (size_t)(i0 + sr) * DD;
  const size_t gb = (size_t)(j0 + sr) * DD;

  for (int kk = 0; kk < DD; kk += 32) {
    __syncthreads();
    uint4 ah0 = *(const uint4*)&Ehi[ga + kk + c0];
    uint4 ah1 = *(const uint4*)&Ehi[ga + kk + c0 + 8];
    uint4 al0 = *(const uint4*)&Elo[ga + kk + c0];
    uint4 al1 = *(const uint4*)&Elo[ga + kk + c0 + 8];
    uint4 bh0 = *(const uint4*)&Ehi[gb + kk + c0];
    uint4 bh1 = *(const uint4*)&Ehi[gb + kk + c0 + 8];
    uint4 bl0 = *(const uint4*)&Elo[gb + kk + c0];
    uint4 bl1 = *(const uint4*)&Elo[gb + kk + c0 + 8];
    *(uint4*)&S[OF_AH + sr * TSTR + c0] = ah0;
    *(uint4*)&S[OF_AH + sr * TSTR + c0 + 8] = ah1;
    *(uint4*)&S[OF_AL + sr * TSTR + c0] = al0;
    *(uint4*)&S[OF_AL + sr * TSTR + c0 + 8] = al1;
    *(uint4*)&S[OF_BH + sr * TSTR + c0] = bh0;
    *(uint4*)&S[OF_BH + sr * TSTR + c0 + 8] = bh1;
    *(uint4*)&S[OF_BL + sr * TSTR + c0] = bl0;
    *(uint4*)&S[OF_BL + sr * TSTR + c0 + 8] = bl1;
    __syncthreads();

    short8 ah[4], al[4], bh[4];
#pragma unroll
    for (int mt = 0; mt < 4; ++mt) {
      int rr = (wr * 64 + mt * 16 + l16) * TSTR + quad * 8;
      ah[mt] = *(const short8*)&S[OF_AH + rr];
      al[mt] = *(const short8*)&S[OF_AL + rr];
    }
#pragma unroll
    for (int nt = 0; nt < 4; ++nt)
      bh[nt] = *(const short8*)&S[OF_BH + (wc * 64 + nt * 16 + l16) * TSTR + quad * 8];
#pragma unroll
    for (int mt = 0; mt < 4; ++mt)
#pragma unroll
      for (int nt = 0; nt < 4; ++nt)
        acc[mt][nt] = __builtin_amdgcn_mfma_f32_16x16x32_bf16(ah[mt], bh[nt], acc[mt][nt], 0, 0, 0);
#pragma unroll
    for (int mt = 0; mt < 4; ++mt)
#pragma unroll
      for (int nt = 0; nt < 4; ++nt)
        acc[mt][nt] = __builtin_amdgcn_mfma_f32_16x16x32_bf16(al[mt], bh[nt], acc[mt][nt], 0, 0, 0);
    short8 bl[4];
#pragma unroll
    for (int nt = 0; nt < 4; ++nt)
      bl[nt] = *(const short8*)&S[OF_BL + (wc * 64 + nt * 16 + l16) * TSTR + quad * 8];
#pragma unroll
    for (int mt = 0; mt < 4; ++mt)
#pragma unroll
      for (int nt = 0; nt < 4; ++nt)
        acc[mt][nt] = __builtin_amdgcn_mfma_f32_16x16x32_bf16(ah[mt], bl[nt], acc[mt][nt], 0, 0, 0);
  }

  // --- normal tile write: round-up bf16 into per-row scratch ---
#pragma unroll
  for (int mt = 0; mt < 4; ++mt)
#pragma unroll
    for (int r = 0; r < 4; ++r) {
      int row = i0 + wr * 64 + mt * 16 + quad * 4 + r;
      unsigned short* Br = bfrow(C, row) + j0 + wc * 64;
#pragma unroll
      for (int nt = 0; nt < 4; ++nt) Br[nt * 16 + l16] = f2bf_ru(acc[mt][nt][r]);
    }

  // --- per-row tile-max (rows of this tile) ---
#pragma unroll
  for (int mt = 0; mt < 4; ++mt)
#pragma unroll
    for (int r = 0; r < 4; ++r) {
      float m = fmaxf(fmaxf(acc[mt][0][r], acc[mt][1][r]),
                      fmaxf(acc[mt][2][r], acc[mt][3][r]));
      m = fmaxf(m, __shfl_xor(m, 1));
      m = fmaxf(m, __shfl_xor(m, 2));
      m = fmaxf(m, __shfl_xor(m, 4));
      m = fmaxf(m, __shfl_xor(m, 8));
      if (l16 == 0) rmx[wr * 64 + mt * 16 + quad * 4 + r][wc] = m;
    }
  // --- per-col tile-max (rows of the mirrored tile), only if off-diagonal ---
  if (bx > by) {
#pragma unroll
    for (int nt = 0; nt < 4; ++nt) {
      float c = -FLT_MAX;
#pragma unroll
      for (int mt = 0; mt < 4; ++mt)
#pragma unroll
        for (int r = 0; r < 4; ++r) c = fmaxf(c, acc[mt][nt][r]);
      c = fmaxf(c, __shfl_xor(c, 16));
      c = fmaxf(c, __shfl_xor(c, 32));
      if (quad == 0) cmx[wc * 64 + nt * 16 + l16][wr] = c;
    }
  }
  __syncthreads();
  if (t < 128) TM[(size_t)(i0 + t) * 64 + bx] = fmaxf(rmx[t][0], rmx[t][1]);
  if (bx > by) {
    if (t < 128) TM[(size_t)(j0 + t) * 64 + by] = fmaxf(cmx[t][0], cmx[t][1]);
    // --- transposed mirror write via LDS strips (Tt aliases S), bf16-RU out ---
    for (int s = 0; s < 2; ++s) {
      __syncthreads();
      if (wc == s) {
#pragma unroll
        for (int mt = 0; mt < 4; ++mt)
#pragma unroll
          for (int nt = 0; nt < 4; ++nt)
#pragma unroll
            for (int r = 0; r < 4; ++r)
              Tt[nt * 16 + l16][wr * 64 + mt * 16 + quad * 4 + r] = acc[mt][nt][r];
      }
      __syncthreads();
#pragma unroll
      for (int q = 0; q < 8; ++q) {
        int fi = q * 256 + t;
        int rr = fi >> 5;
        int cc4 = (fi & 31) * 4;
        ushort4 v;
        v.x = f2bf_ru(Tt[rr][cc4]);
        v.y = f2bf_ru(Tt[rr][cc4 + 1]);
        v.z = f2bf_ru(Tt[rr][cc4 + 2]);
        v.w = f2bf_ru(Tt[rr][cc4 + 3]);
        *(ushort4*)(bfrow(C, j0 + s * 64 + rr) + i0 + cc4) = v;
      }
    }
  }
}

// ---------------------------------------------------------------------------
// Kernel C1: collect. One WAVE per row. T = 31st largest tile-max via O(64)
// rank-select. Single pass over the bf16-RU row scratch collects cands
// >= T - 2*DELTA (sound: stored >= approx); exact fmaf chains re-rank;
// emit KV[row][31] = (idx, relu(exact)). Overflow -> flag. No output write.
// LDS ~14.1KB -> 8 blocks/CU -> full 32-wave occupancy.
// ---------------------------------------------------------------------------
__global__ __launch_bounds__(256) void topk_collect(
    const float* __restrict__ C, const float* __restrict__ e32,
    const float* __restrict__ TM, int* __restrict__ flags,
    int2* __restrict__ KV) {
  const int w = threadIdx.x >> 6;
  const int lane = threadIdx.x & 63;
  const int row = blockIdx.x * 4 + w;

  __shared__ float er[4][DD];
  __shared__ int cidx[4][CAPW];
  __shared__ float cval[4][CAPW];
  __shared__ int wcnt[4];

  {
    const float4* e4 = (const float4*)(e32 + (size_t)row * DD);
    float4* er4 = (float4*)er[w];
    er4[lane] = e4[lane];
    er4[64 + lane] = e4[64 + lane];
  }
  if (lane == 0) wcnt[w] = 0;

  // T = 31st largest of 64 tile maxima: rank-select with independent shuffles.
  float mv = TM[(size_t)row * 64 + lane];
  unsigned key = ordmap(mv);
  int rank = 0;
#pragma unroll
  for (int off = 1; off < 64; ++off) {
    int ol = (lane + off) & 63;
    unsigned ok = __shfl(key, ol);
    rank += (ok > key || (ok == key && ol < lane)) ? 1 : 0;
  }
  unsigned long long bmsk = __ballot(rank == TOPK - 1);
  float T = __shfl(mv, __ffsll((unsigned long long)bmsk) - 1);

  // single row pass over bf16-RU scratch: collect candidates
  const float Tc = T - 2.0f * DELTA;
  const unsigned short* Brow =
      (const unsigned short*)C + (size_t)row * (2 * NN) + NN;
  const uint4* Br4 = (const uint4*)Brow;
  for (int it = 0; it < NN / 512; ++it) {
    uint4 v = Br4[it * 64 + lane];
    int j = (it * 64 + lane) * 8;
    unsigned wv[4] = {v.x, v.y, v.z, v.w};
#pragma unroll
    for (int c = 0; c < 4; ++c) {
      float f0 = __uint_as_float(wv[c] << 16);
      float f1 = __uint_as_float(wv[c] & 0xffff0000u);
      if (f0 >= Tc) { int p = atomicAdd(&wcnt[w], 1); if (p < CAPW) cidx[w][p] = j + 2 * c; }
      if (f1 >= Tc) { int p = atomicAdd(&wcnt[w], 1); if (p < CAPW) cidx[w][p] = j + 2 * c + 1; }
    }
  }
  const int cnt = wcnt[w];

  if (cnt > CAPW) {
    if (lane == 0) flags[row] = 1;
    return;
  }

  // exact sequential-k fmaf chains (bit-identical to the verified chain)
  for (int c = lane; c < cnt; c += 64) {
    const float4* ej4 = (const float4*)(e32 + (size_t)cidx[w][c] * DD);
    float a = 0.f;
    for (int k4 = 0; k4 < DD / 4; ++k4) {
      float4 vv = ej4[k4];
      const float* e = &er[w][k4 * 4];
      a = fmaf(e[0], vv.x, a);
      a = fmaf(e[1], vv.y, a);
      a = fmaf(e[2], vv.z, a);
      a = fmaf(e[3], vv.w, a);
    }
    cval[w][c] = a;
  }

  // stable top-31 by (exact desc, idx asc) -> KV pairs
  for (int c = lane; c < cnt; c += 64) {
    float v = cval[w][c];
    int idx = cidx[w][c];
    int rnk = 0;
    for (int c2 = 0; c2 < cnt; ++c2) {
      float v2 = cval[w][c2];
      if (v2 > v || (v2 == v && cidx[w][c2] < idx)) ++rnk;
    }
    if (rnk < TOPK)
      KV[(size_t)row * TOPK + rnk] =
          make_int2(idx, __float_as_int(fmaxf(v, 0.0f)));
  }
}

// ---------------------------------------------------------------------------
// Kernel C2: writer. One block per row: streaming float4 zero-fill of the
// 32KB row (also overwrites the bf16 scratch half), barrier (drains stores),
// then lanes 0..30 scatter the 31 values. Pure write-BW bound.
// Flagged rows: indices masked for safety; cleanup rewrites the row after.
// ---------------------------------------------------------------------------
__global__ __launch_bounds__(256) void write_kernel(float* __restrict__ C,
                                                    const int2* __restrict__ KV) {
  const int row = blockIdx.x;
  const int t = threadIdx.x;
  int j = 0;
  float v = 0.f;
  if (t < TOPK) {
    int2 p = KV[(size_t)row * TOPK + t];
    j = p.x & (NN - 1);
    v = __int_as_float(p.y);
  }
  const float4 z = make_float4(0.f, 0.f, 0.f, 0.f);
  float4* Cw4 = (float4*)(C + (size_t)row * NN);
#pragma unroll
  for (int i = 0; i < NN / 4 / 256; ++i) Cw4[i * 256 + t] = z;
  __syncthreads();  // vmcnt(0) drain: zeros committed before value stores
  if (t < TOPK) C[(size_t)row * NN + j] = v;
}

// ---------------------------------------------------------------------------
// Kernel D: exact cleanup for flagged rows (statistically never executes).
// ---------------------------------------------------------------------------
__global__ __launch_bounds__(256) void cleanup_kernel(
    float* __restrict__ C, const float* __restrict__ e32,
    const int* __restrict__ flags) {
  const int row = blockIdx.x;
  if (flags[row] == 0) return;
  const int tid = threadIdx.x;
  const int lane = tid & 63, wid = tid >> 6;

  __shared__ float sv[NN];
  __shared__ float er[DD];
  __shared__ unsigned long long wred[4];
  __shared__ int kidx[TOPK];
  __shared__ float kval[TOPK];

  {
    const float4* e4 = (const float4*)(e32 + (size_t)row * DD);
    if (tid < DD / 4) ((float4*)er)[tid] = e4[tid];
  }
  __syncthreads();

  for (int m = 0; m < NN / 256; ++m) {
    int j = m * 256 + tid;
    const float* ej = e32 + (size_t)j * DD;
    float a = 0.f;
    for (int k = 0; k < DD; k += 4) {
      float4 v = *(const float4*)&ej[k];
      a = fmaf(er[k], v.x, a);
      a = fmaf(er[k + 1], v.y, a);
      a = fmaf(er[k + 2], v.z, a);
      a = fmaf(er[k + 3], v.w, a);
    }
    sv[j] = a;
  }
  __syncthreads();

  for (int it = 0; it < TOPK; ++it) {
    float bv = -FLT_MAX;
    int bi = 0;
    for (int j = tid; j < NN; j += 256) {
      float v = sv[j];
      if (v > bv) { bv = v; bi = j; }
    }
    unsigned long long key =
        ((unsigned long long)ordmap(bv) << 32) | (unsigned)(NN - 1 - bi);
#pragma unroll
    for (int off = 32; off; off >>= 1) {
      unsigned long long o = __shfl_xor(key, off);
      if (o > key) key = o;
    }
    if (lane == 0) wred[wid] = key;
    __syncthreads();
    if (tid == 0) {
      unsigned long long k0 = wred[0];
      if (wred[1] > k0) k0 = wred[1];
      if (wred[2] > k0) k0 = wred[2];
      if (wred[3] > k0) k0 = wred[3];
      int idx = (NN - 1) - (int)(k0 & 0xFFFFFFFFu);
      kidx[it] = idx;
      kval[it] = sv[idx];
      sv[idx] = -FLT_MAX;
    }
    __syncthreads();
  }

  float4 z4 = make_float4(0.f, 0.f, 0.f, 0.f);
  float4* sv4 = (float4*)sv;
  for (int i = tid; i < NN / 4; i += 256) sv4[i] = z4;
  __syncthreads();
  if (tid < TOPK) sv[kidx[tid]] = fmaxf(kval[tid], 0.0f);
  __syncthreads();
  float4* Cw4 = (float4*)(C + (size_t)row * NN);
  for (int i = tid; i < NN / 4; i += 256) Cw4[i] = sv4[i];
}

// ---------------------------------------------------------------------------
extern "C" void kernel_launch(void* const* d_in, const int* in_sizes, int n_in,
                              void* d_out, int out_size, void* d_ws,
                              size_t ws_size, hipStream_t stream) {
  const float* f = (const float*)d_in[0];
  const float* W1 = (const float*)d_in[1];
  const float* W2 = (const float*)d_in[2];
  float* out = (float*)d_out;
  char* ws = (char*)d_ws;
  float* e32 = (float*)ws;                                     // 16 MiB
  unsigned short* Ehi = (unsigned short*)(ws + (size_t)NN * DD * 4);   // 8 MiB
  unsigned short* Elo = (unsigned short*)(ws + (size_t)NN * DD * 6);   // 8 MiB
  float* TM = (float*)(ws + (size_t)NN * DD * 8);              // 2 MiB
  int* flags = (int*)(ws + (size_t)NN * DD * 8 + (size_t)NN * 64 * 4);  // 32 KB
  int2* KV = (int2*)(ws + (size_t)NN * DD * 8 + (size_t)NN * 64 * 4 +
                     (size_t)NN * 8);  // ~2 MiB (8192*31*8 B)

  emb_kernel<<<NN / 4, 256, 0, stream>>>(f, W1, W2, e32, Ehi, Elo, flags);
  dim3 g2(NN / 128, NN / 128);
  sim_mfma<<<g2, 256, 0, stream>>>(Ehi, Elo, out, TM);
  topk_collect<<<NN / 4, 256, 0, stream>>>(out, e32, TM, flags, KV);
  write_kernel<<<NN, 256, 0, stream>>>(out, KV);
  cleanup_kernel<<<NN, 256, 0, stream>>>(out, e32, flags);
}

// Round 3
// 580.280 us; speedup vs baseline: 1.1608x; 1.0616x over previous
//
#include <hip/hip_runtime.h>
#include <float.h>
#include <math.h>

// Problem constants (fixed by the reference: N=8192, D=512, k+1=31).
#define NN 8192
#define DD 512
#define TOPK 31
#define CAPW 192          // per-wave candidate cap (typical cnt ~50)
#define DELTA 1e-4f       // sound |approx-exact| bound: lo*lo + requant ~5e-5

// Strategy (R10):
//   Bit-exact value chain (absmax 0.0 since R3):
//     h = relu(f*W1)*W2 ; n = sqrtf(numpy-pairwise sum h*h) ; e = h/n
//     sim[i][j] = sequential-k fmaf chain over e_i*e_j ; stable top-31
//   Approx sim = bf16 MFMA: e = hi+lo, acc = hi*hi + lo*hi + hi*lo.
//   NEW (R10): sim_mfma K-loop rebuilt in the m97 shape:
//     - global_load_lds width=16 direct staging (no VGPR round-trip)
//     - linear [128][32-short] LDS tiles (conflict-free for b128 frag reads,
//       required by gload_lds's wave-uniform-base+lane*16 dest rule)
//     - 32KB tiles + 2KB maxima + 34KB epilogue alias -> 4 blocks/CU
//     - 1D triangular grid (2080 blocks, no dead bx<by blocks)
//     - transposed-mirror LDS stride 132->133 (kills 8-way write conflict)
//   sim scratch stored as ROUND-UP bf16 in the SECOND 16KB of each output
//   f32 row; topk_collect (latency phase) -> KV pairs; write_kernel (BW
//   phase) streams zeros + scatters 31 values; cleanup for flagged rows.

typedef __attribute__((ext_vector_type(8))) short short8;
typedef __attribute__((ext_vector_type(4))) float f32x4;

__device__ __forceinline__ float h_elem(const float* __restrict__ f,
                                        const float* __restrict__ W1,
                                        const float* __restrict__ W2, int k) {
  float x = f[k] * W1[k];
  x = fmaxf(x, 0.0f);
  return x * W2[k];
}

__device__ __forceinline__ unsigned short f2bf_rne(float x) {
  unsigned u = __float_as_uint(x);
  unsigned r = (u >> 16) & 1u;
  u += 0x7fffu + r;
  return (unsigned short)(u >> 16);
}
// Round toward +inf: guarantees bf16(x) >= x. (pos: ceil; neg: trunc->up)
__device__ __forceinline__ unsigned short f2bf_ru(float x) {
  unsigned u = __float_as_uint(x);
  if (!(u >> 31)) u += 0xffffu;
  return (unsigned short)(u >> 16);
}
__device__ __forceinline__ float bf2f(unsigned short h) {
  return __uint_as_float(((unsigned)h) << 16);
}
__device__ __forceinline__ unsigned ordmap(float x) {
  unsigned u = __float_as_uint(x);
  return (u & 0x80000000u) ? ~u : (u | 0x80000000u);
}

// async global->LDS, 16B per lane (dest = wave-uniform base + lane*16)
__device__ __forceinline__ void gl16(const void* g, void* l) {
  __builtin_amdgcn_global_load_lds(
      (const __attribute__((address_space(1))) void*)g,
      (__attribute__((address_space(3))) void*)l, 16, 0, 0);
}

// bf16 scratch image of sim row i: second half of output row i's 32KB span.
__device__ __forceinline__ unsigned short* bfrow(float* C, int row) {
  return (unsigned short*)C + (size_t)row * (2 * NN) + NN;
}

// ---------------------------------------------------------------------------
// Kernel A: fused norm (numpy pairwise association, bit-exact) + e = h/n,
// bf16 hi/lo split (RNE), flag zeroing. One wave per row.
// ---------------------------------------------------------------------------
__global__ __launch_bounds__(256) void emb_kernel(
    const float* __restrict__ f, const float* __restrict__ W1,
    const float* __restrict__ W2, float* __restrict__ e32,
    unsigned short* __restrict__ Ehi, unsigned short* __restrict__ Elo,
    int* __restrict__ flags) {
  const int lane = threadIdx.x & 63;
  const int row = blockIdx.x * 4 + (threadIdx.x >> 6);
  const float* fr = f + (size_t)row * DD;
  const int b = lane >> 4, L = lane & 15;
  if (lane == 0) flags[row] = 0;

  float s[8];
#pragma unroll
  for (int j = 0; j < 8; ++j) {
    float h = h_elem(fr, W1, W2, b * 128 + 16 * j + L);
    s[j] = h * h;
  }
  float v = ((s[0] + s[1]) + (s[2] + s[3])) + ((s[4] + s[5]) + (s[6] + s[7]));
  float t = v + __shfl_xor(v, 8);
  t = t + __shfl_xor(t, 4);
  t = t + __shfl_xor(t, 2);
  float nb = t + __shfl_xor(t, 1);
  float x = nb + __shfl_xor(nb, 16);
  float norm2 = x + __shfl_xor(x, 32);
  const float n = fmaxf(sqrtf(norm2), 1e-12f);

  float* er = e32 + (size_t)row * DD;
  unsigned short* hr = Ehi + (size_t)row * DD;
  unsigned short* lr = Elo + (size_t)row * DD;
#pragma unroll
  for (int m = 0; m < 8; ++m) {
    int k = m * 64 + lane;
    float e = h_elem(fr, W1, W2, k) / n;
    er[k] = e;
    unsigned short hb = f2bf_rne(e);
    hr[k] = hb;
    lr[k] = f2bf_rne(e - bf2f(hb));
  }
}

// ---------------------------------------------------------------------------
// Kernel B: merged 3-term bf16 MFMA sim, upper-triangle 128x128 tiles.
// m97-shape K-loop (BK=32): global_load_lds x8 -> barrier -> 16 frag reads +
// 48 MFMAs -> barrier. Linear LDS tiles AH|AL|BH|BL, 8KB each.
// Epilogue: round-up bf16 tile write into per-row scratch halves + per-row
// tile-max TM + (bx>by) transposed mirror tile via LDS strips + transposed TM.
// ---------------------------------------------------------------------------
#define OFS_AL 4096   // short offsets into S
#define OFS_BH 8192
#define OFS_BL 12288

__global__ __launch_bounds__(256) void sim_mfma(
    const unsigned short* __restrict__ Ehi,
    const unsigned short* __restrict__ Elo, float* __restrict__ C,
    float* __restrict__ TM) {
  // triangular decode: 2080 blocks -> (bx, by) with bx >= by
  int rem = blockIdx.x, by = 0;
  while (rem >= 64 - by) { rem -= 64 - by; ++by; }
  const int bx = by + rem;

  __shared__ __align__(16) char smem[34048];  // K-loop: 32KB tiles; epi: Tt
  unsigned short* S = (unsigned short*)smem;
  char* Sc = smem;
  float(*Tt)[133] = (float(*)[133])smem;  // epilogue alias (34048 B)
  __shared__ float rmx[128][2];
  __shared__ float cmx[128][2];

  const int t = threadIdx.x;
  const int lane = t & 63, w = t >> 6;
  const int wr = w >> 1, wc = w & 1;
  const int quad = lane >> 4, l16 = lane & 15;
  const int i0 = by * 128, j0 = bx * 128;

  f32x4 acc[4][4];
#pragma unroll
  for (int a = 0; a < 4; ++a)
#pragma unroll
    for (int b = 0; b < 4; ++b) acc[a][b] = (f32x4){0.f, 0.f, 0.f, 0.f};

  // staging addresses: lane ln of wave w writes LDS byte (h*4096 + w*1024 +
  // ln*16) of a tensor == row (h*64 + t>>2), chunk (t&3) of [128][32sh].
  const size_t rA = (size_t)(i0 + (t >> 2)) * DD + (t & 3) * 8;
  const size_t rB = (size_t)(j0 + (t >> 2)) * DD + (t & 3) * 8;
  const size_t H = (size_t)64 * DD;
  char* L0 = Sc + (w << 10);  // wave-uniform LDS base (+h*4096, +tensor ofs)

  for (int kk = 0; kk < DD; kk += 32) {
    gl16(Ehi + rA + kk, L0);
    gl16(Ehi + rA + H + kk, L0 + 4096);
    gl16(Elo + rA + kk, L0 + 8192);
    gl16(Elo + rA + H + kk, L0 + 8192 + 4096);
    gl16(Ehi + rB + kk, L0 + 16384);
    gl16(Ehi + rB + H + kk, L0 + 16384 + 4096);
    gl16(Elo + rB + kk, L0 + 24576);
    gl16(Elo + rB + H + kk, L0 + 24576 + 4096);
    __syncthreads();  // drains vmcnt: tiles resident

    short8 ah[4], al[4], bh[4];
#pragma unroll
    for (int mt = 0; mt < 4; ++mt) {
      int rr = (wr * 64 + mt * 16 + l16) * 32 + quad * 8;
      ah[mt] = *(const short8*)&S[rr];
      al[mt] = *(const short8*)&S[OFS_AL + rr];
    }
#pragma unroll
    for (int nt = 0; nt < 4; ++nt)
      bh[nt] = *(const short8*)&S[OFS_BH + (wc * 64 + nt * 16 + l16) * 32 + quad * 8];
#pragma unroll
    for (int mt = 0; mt < 4; ++mt)
#pragma unroll
      for (int nt = 0; nt < 4; ++nt)
        acc[mt][nt] = __builtin_amdgcn_mfma_f32_16x16x32_bf16(ah[mt], bh[nt], acc[mt][nt], 0, 0, 0);
#pragma unroll
    for (int mt = 0; mt < 4; ++mt)
#pragma unroll
      for (int nt = 0; nt < 4; ++nt)
        acc[mt][nt] = __builtin_amdgcn_mfma_f32_16x16x32_bf16(al[mt], bh[nt], acc[mt][nt], 0, 0, 0);
    short8 bl[4];
#pragma unroll
    for (int nt = 0; nt < 4; ++nt)
      bl[nt] = *(const short8*)&S[OFS_BL + (wc * 64 + nt * 16 + l16) * 32 + quad * 8];
#pragma unroll
    for (int mt = 0; mt < 4; ++mt)
#pragma unroll
      for (int nt = 0; nt < 4; ++nt)
        acc[mt][nt] = __builtin_amdgcn_mfma_f32_16x16x32_bf16(ah[mt], bl[nt], acc[mt][nt], 0, 0, 0);
    __syncthreads();  // frag reads done before next stage overwrites
  }

  // --- normal tile write: round-up bf16 into per-row scratch ---
#pragma unroll
  for (int mt = 0; mt < 4; ++mt)
#pragma unroll
    for (int r = 0; r < 4; ++r) {
      int row = i0 + wr * 64 + mt * 16 + quad * 4 + r;
      unsigned short* Br = bfrow(C, row) + j0 + wc * 64;
#pragma unroll
      for (int nt = 0; nt < 4; ++nt) Br[nt * 16 + l16] = f2bf_ru(acc[mt][nt][r]);
    }

  // --- per-row tile-max (rows of this tile) ---
#pragma unroll
  for (int mt = 0; mt < 4; ++mt)
#pragma unroll
    for (int r = 0; r < 4; ++r) {
      float m = fmaxf(fmaxf(acc[mt][0][r], acc[mt][1][r]),
                      fmaxf(acc[mt][2][r], acc[mt][3][r]));
      m = fmaxf(m, __shfl_xor(m, 1));
      m = fmaxf(m, __shfl_xor(m, 2));
      m = fmaxf(m, __shfl_xor(m, 4));
      m = fmaxf(m, __shfl_xor(m, 8));
      if (l16 == 0) rmx[wr * 64 + mt * 16 + quad * 4 + r][wc] = m;
    }
  // --- per-col tile-max (rows of the mirrored tile), only if off-diagonal ---
  if (bx > by) {
#pragma unroll
    for (int nt = 0; nt < 4; ++nt) {
      float c = -FLT_MAX;
#pragma unroll
      for (int mt = 0; mt < 4; ++mt)
#pragma unroll
        for (int r = 0; r < 4; ++r) c = fmaxf(c, acc[mt][nt][r]);
      c = fmaxf(c, __shfl_xor(c, 16));
      c = fmaxf(c, __shfl_xor(c, 32));
      if (quad == 0) cmx[wc * 64 + nt * 16 + l16][wr] = c;
    }
  }
  __syncthreads();
  if (t < 128) TM[(size_t)(i0 + t) * 64 + bx] = fmaxf(rmx[t][0], rmx[t][1]);
  if (bx > by) {
    if (t < 128) TM[(size_t)(j0 + t) * 64 + by] = fmaxf(cmx[t][0], cmx[t][1]);
    // --- transposed mirror write via LDS strips (Tt aliases S), bf16-RU out ---
    for (int s = 0; s < 2; ++s) {
      __syncthreads();
      if (wc == s) {
#pragma unroll
        for (int mt = 0; mt < 4; ++mt)
#pragma unroll
          for (int nt = 0; nt < 4; ++nt)
#pragma unroll
            for (int r = 0; r < 4; ++r)
              Tt[nt * 16 + l16][wr * 64 + mt * 16 + quad * 4 + r] = acc[mt][nt][r];
      }
      __syncthreads();
#pragma unroll
      for (int q = 0; q < 8; ++q) {
        int fi = q * 256 + t;
        int rr = fi >> 5;
        int cc4 = (fi & 31) * 4;
        ushort4 v;
        v.x = f2bf_ru(Tt[rr][cc4]);
        v.y = f2bf_ru(Tt[rr][cc4 + 1]);
        v.z = f2bf_ru(Tt[rr][cc4 + 2]);
        v.w = f2bf_ru(Tt[rr][cc4 + 3]);
        *(ushort4*)(bfrow(C, j0 + s * 64 + rr) + i0 + cc4) = v;
      }
    }
  }
}

// ---------------------------------------------------------------------------
// Kernel C1: collect. One WAVE per row. T = 31st largest tile-max via O(64)
// rank-select. Single pass over the bf16-RU row scratch collects cands
// >= T - 2*DELTA (sound: stored >= approx); exact fmaf chains re-rank;
// emit KV[row][31] = (idx, relu(exact)). Overflow -> flag. No output write.
// ---------------------------------------------------------------------------
__global__ __launch_bounds__(256) void topk_collect(
    const float* __restrict__ C, const float* __restrict__ e32,
    const float* __restrict__ TM, int* __restrict__ flags,
    int2* __restrict__ KV) {
  const int w = threadIdx.x >> 6;
  const int lane = threadIdx.x & 63;
  const int row = blockIdx.x * 4 + w;

  __shared__ float er[4][DD];
  __shared__ int cidx[4][CAPW];
  __shared__ float cval[4][CAPW];
  __shared__ int wcnt[4];

  {
    const float4* e4 = (const float4*)(e32 + (size_t)row * DD);
    float4* er4 = (float4*)er[w];
    er4[lane] = e4[lane];
    er4[64 + lane] = e4[64 + lane];
  }
  if (lane == 0) wcnt[w] = 0;

  // T = 31st largest of 64 tile maxima: rank-select with independent shuffles.
  float mv = TM[(size_t)row * 64 + lane];
  unsigned key = ordmap(mv);
  int rank = 0;
#pragma unroll
  for (int off = 1; off < 64; ++off) {
    int ol = (lane + off) & 63;
    unsigned ok = __shfl(key, ol);
    rank += (ok > key || (ok == key && ol < lane)) ? 1 : 0;
  }
  unsigned long long bmsk = __ballot(rank == TOPK - 1);
  float T = __shfl(mv, __ffsll((unsigned long long)bmsk) - 1);

  // single row pass over bf16-RU scratch: collect candidates
  const float Tc = T - 2.0f * DELTA;
  const unsigned short* Brow =
      (const unsigned short*)C + (size_t)row * (2 * NN) + NN;
  const uint4* Br4 = (const uint4*)Brow;
  for (int it = 0; it < NN / 512; ++it) {
    uint4 v = Br4[it * 64 + lane];
    int j = (it * 64 + lane) * 8;
    unsigned wv[4] = {v.x, v.y, v.z, v.w};
#pragma unroll
    for (int c = 0; c < 4; ++c) {
      float f0 = __uint_as_float(wv[c] << 16);
      float f1 = __uint_as_float(wv[c] & 0xffff0000u);
      if (f0 >= Tc) { int p = atomicAdd(&wcnt[w], 1); if (p < CAPW) cidx[w][p] = j + 2 * c; }
      if (f1 >= Tc) { int p = atomicAdd(&wcnt[w], 1); if (p < CAPW) cidx[w][p] = j + 2 * c + 1; }
    }
  }
  const int cnt = wcnt[w];

  if (cnt > CAPW) {
    if (lane == 0) flags[row] = 1;
    return;
  }

  // exact sequential-k fmaf chains (bit-identical to the verified chain)
  for (int c = lane; c < cnt; c += 64) {
    const float4* ej4 = (const float4*)(e32 + (size_t)cidx[w][c] * DD);
    float a = 0.f;
    for (int k4 = 0; k4 < DD / 4; ++k4) {
      float4 vv = ej4[k4];
      const float* e = &er[w][k4 * 4];
      a = fmaf(e[0], vv.x, a);
      a = fmaf(e[1], vv.y, a);
      a = fmaf(e[2], vv.z, a);
      a = fmaf(e[3], vv.w, a);
    }
    cval[w][c] = a;
  }

  // stable top-31 by (exact desc, idx asc) -> KV pairs
  for (int c = lane; c < cnt; c += 64) {
    float v = cval[w][c];
    int idx = cidx[w][c];
    int rnk = 0;
    for (int c2 = 0; c2 < cnt; ++c2) {
      float v2 = cval[w][c2];
      if (v2 > v || (v2 == v && cidx[w][c2] < idx)) ++rnk;
    }
    if (rnk < TOPK)
      KV[(size_t)row * TOPK + rnk] =
          make_int2(idx, __float_as_int(fmaxf(v, 0.0f)));
  }
}

// ---------------------------------------------------------------------------
// Kernel C2: writer. One block per row: streaming float4 zero-fill of the
// 32KB row (also overwrites the bf16 scratch half), barrier (drains stores),
// then lanes 0..30 scatter the 31 values. Pure write-BW bound.
// ---------------------------------------------------------------------------
__global__ __launch_bounds__(256) void write_kernel(float* __restrict__ C,
                                                    const int2* __restrict__ KV) {
  const int row = blockIdx.x;
  const int t = threadIdx.x;
  int j = 0;
  float v = 0.f;
  if (t < TOPK) {
    int2 p = KV[(size_t)row * TOPK + t];
    j = p.x & (NN - 1);
    v = __int_as_float(p.y);
  }
  const float4 z = make_float4(0.f, 0.f, 0.f, 0.f);
  float4* Cw4 = (float4*)(C + (size_t)row * NN);
#pragma unroll
  for (int i = 0; i < NN / 4 / 256; ++i) Cw4[i * 256 + t] = z;
  __syncthreads();  // vmcnt(0) drain: zeros committed before value stores
  if (t < TOPK) C[(size_t)row * NN + j] = v;
}

// ---------------------------------------------------------------------------
// Kernel D: exact cleanup for flagged rows (statistically never executes).
// ---------------------------------------------------------------------------
__global__ __launch_bounds__(256) void cleanup_kernel(
    float* __restrict__ C, const float* __restrict__ e32,
    const int* __restrict__ flags) {
  const int row = blockIdx.x;
  if (flags[row] == 0) return;
  const int tid = threadIdx.x;
  const int lane = tid & 63, wid = tid >> 6;

  __shared__ float sv[NN];
  __shared__ float er[DD];
  __shared__ unsigned long long wred[4];
  __shared__ int kidx[TOPK];
  __shared__ float kval[TOPK];

  {
    const float4* e4 = (const float4*)(e32 + (size_t)row * DD);
    if (tid < DD / 4) ((float4*)er)[tid] = e4[tid];
  }
  __syncthreads();

  for (int m = 0; m < NN / 256; ++m) {
    int j = m * 256 + tid;
    const float* ej = e32 + (size_t)j * DD;
    float a = 0.f;
    for (int k = 0; k < DD; k += 4) {
      float4 v = *(const float4*)&ej[k];
      a = fmaf(er[k], v.x, a);
      a = fmaf(er[k + 1], v.y, a);
      a = fmaf(er[k + 2], v.z, a);
      a = fmaf(er[k + 3], v.w, a);
    }
    sv[j] = a;
  }
  __syncthreads();

  for (int it = 0; it < TOPK; ++it) {
    float bv = -FLT_MAX;
    int bi = 0;
    for (int j = tid; j < NN; j += 256) {
      float v = sv[j];
      if (v > bv) { bv = v; bi = j; }
    }
    unsigned long long key =
        ((unsigned long long)ordmap(bv) << 32) | (unsigned)(NN - 1 - bi);
#pragma unroll
    for (int off = 32; off; off >>= 1) {
      unsigned long long o = __shfl_xor(key, off);
      if (o > key) key = o;
    }
    if (lane == 0) wred[wid] = key;
    __syncthreads();
    if (tid == 0) {
      unsigned long long k0 = wred[0];
      if (wred[1] > k0) k0 = wred[1];
      if (wred[2] > k0) k0 = wred[2];
      if (wred[3] > k0) k0 = wred[3];
      int idx = (NN - 1) - (int)(k0 & 0xFFFFFFFFu);
      kidx[it] = idx;
      kval[it] = sv[idx];
      sv[idx] = -FLT_MAX;
    }
    __syncthreads();
  }

  float4 z4 = make_float4(0.f, 0.f, 0.f, 0.f);
  float4* sv4 = (float4*)sv;
  for (int i = tid; i < NN / 4; i += 256) sv4[i] = z4;
  __syncthreads();
  if (tid < TOPK) sv[kidx[tid]] = fmaxf(kval[tid], 0.0f);
  __syncthreads();
  float4* Cw4 = (float4*)(C + (size_t)row * NN);
  for (int i = tid; i < NN / 4; i += 256) Cw4[i] = sv4[i];
}

// ---------------------------------------------------------------------------
extern "C" void kernel_launch(void* const* d_in, const int* in_sizes, int n_in,
                              void* d_out, int out_size, void* d_ws,
                              size_t ws_size, hipStream_t stream) {
  const float* f = (const float*)d_in[0];
  const float* W1 = (const float*)d_in[1];
  const float* W2 = (const float*)d_in[2];
  float* out = (float*)d_out;
  char* ws = (char*)d_ws;
  float* e32 = (float*)ws;                                     // 16 MiB
  unsigned short* Ehi = (unsigned short*)(ws + (size_t)NN * DD * 4);   // 8 MiB
  unsigned short* Elo = (unsigned short*)(ws + (size_t)NN * DD * 6);   // 8 MiB
  float* TM = (float*)(ws + (size_t)NN * DD * 8);              // 2 MiB
  int* flags = (int*)(ws + (size_t)NN * DD * 8 + (size_t)NN * 64 * 4);  // 32 KB
  int2* KV = (int2*)(ws + (size_t)NN * DD * 8 + (size_t)NN * 64 * 4 +
                     (size_t)NN * 8);  // ~2 MiB (8192*31*8 B)

  emb_kernel<<<NN / 4, 256, 0, stream>>>(f, W1, W2, e32, Ehi, Elo, flags);
  sim_mfma<<<2080, 256, 0, stream>>>(Ehi, Elo, out, TM);
  topk_collect<<<NN / 4, 256, 0, stream>>>(out, e32, TM, flags, KV);
  write_kernel<<<NN, 256, 0, stream>>>(out, KV);
  cleanup_kernel<<<NN, 256, 0, stream>>>(out, e32, flags);
}

// Round 4
// 567.995 us; speedup vs baseline: 1.1859x; 1.0216x over previous
//
#include <hip/hip_runtime.h>
#include <float.h>
#include <math.h>

// Problem constants (fixed by the reference: N=8192, D=512, k+1=31).
#define NN 8192
#define DD 512
#define TOPK 31
#define CAPW 192          // per-wave candidate cap (typical cnt ~50)
#define DELTA 1e-4f       // sound |approx-exact| bound: lo*lo + requant ~5e-5

// Strategy (R11):
//   Bit-exact value chain (absmax 0.0 since R3):
//     h = relu(f*W1)*W2 ; n = sqrtf(numpy-pairwise sum h*h) ; e = h/n
//     sim[i][j] = sequential-k fmaf chain over e_i*e_j ; stable top-31
//   Approx sim = bf16 MFMA: e = hi+lo, acc = hi*hi + lo*hi + hi*lo.
//   NEW (R11):
//   - sim_mfma: 2-phase double-buffered pipeline (T3 minimum recipe):
//     issue next k-step's global_load_lds BEFORE computing current buffer,
//     ONE __syncthreads per k-step (its vmcnt0 drain lands after the MFMAs
//     covered the load latency). LDS 2x32KB ping-pong -> 2 blocks/CU.
//   - topk_collect zeroes each row's FIRST 16KB while scanning (free BW in
//     a latency-bound kernel); write_kernel only zeros the second 16KB
//     (the bf16 scratch half) + scatters the 31 values.
//   sim scratch stored as ROUND-UP bf16 in the SECOND 16KB of each output
//   f32 row; collect -> KV pairs; cleanup rewrites flagged rows exactly.

typedef __attribute__((ext_vector_type(8))) short short8;
typedef __attribute__((ext_vector_type(4))) float f32x4;

__device__ __forceinline__ float h_elem(const float* __restrict__ f,
                                        const float* __restrict__ W1,
                                        const float* __restrict__ W2, int k) {
  float x = f[k] * W1[k];
  x = fmaxf(x, 0.0f);
  return x * W2[k];
}

__device__ __forceinline__ unsigned short f2bf_rne(float x) {
  unsigned u = __float_as_uint(x);
  unsigned r = (u >> 16) & 1u;
  u += 0x7fffu + r;
  return (unsigned short)(u >> 16);
}
// Round toward +inf: guarantees bf16(x) >= x. (pos: ceil; neg: trunc->up)
__device__ __forceinline__ unsigned short f2bf_ru(float x) {
  unsigned u = __float_as_uint(x);
  if (!(u >> 31)) u += 0xffffu;
  return (unsigned short)(u >> 16);
}
__device__ __forceinline__ float bf2f(unsigned short h) {
  return __uint_as_float(((unsigned)h) << 16);
}
__device__ __forceinline__ unsigned ordmap(float x) {
  unsigned u = __float_as_uint(x);
  return (u & 0x80000000u) ? ~u : (u | 0x80000000u);
}

// async global->LDS, 16B per lane (dest = wave-uniform base + lane*16)
__device__ __forceinline__ void gl16(const void* g, void* l) {
  __builtin_amdgcn_global_load_lds(
      (const __attribute__((address_space(1))) void*)g,
      (__attribute__((address_space(3))) void*)l, 16, 0, 0);
}

// bf16 scratch image of sim row i: second half of output row i's 32KB span.
__device__ __forceinline__ unsigned short* bfrow(float* C, int row) {
  return (unsigned short*)C + (size_t)row * (2 * NN) + NN;
}

// ---------------------------------------------------------------------------
// Kernel A: fused norm (numpy pairwise association, bit-exact) + e = h/n,
// bf16 hi/lo split (RNE), flag zeroing. One wave per row.
// ---------------------------------------------------------------------------
__global__ __launch_bounds__(256) void emb_kernel(
    const float* __restrict__ f, const float* __restrict__ W1,
    const float* __restrict__ W2, float* __restrict__ e32,
    unsigned short* __restrict__ Ehi, unsigned short* __restrict__ Elo,
    int* __restrict__ flags) {
  const int lane = threadIdx.x & 63;
  const int row = blockIdx.x * 4 + (threadIdx.x >> 6);
  const float* fr = f + (size_t)row * DD;
  const int b = lane >> 4, L = lane & 15;
  if (lane == 0) flags[row] = 0;

  float s[8];
#pragma unroll
  for (int j = 0; j < 8; ++j) {
    float h = h_elem(fr, W1, W2, b * 128 + 16 * j + L);
    s[j] = h * h;
  }
  float v = ((s[0] + s[1]) + (s[2] + s[3])) + ((s[4] + s[5]) + (s[6] + s[7]));
  float t = v + __shfl_xor(v, 8);
  t = t + __shfl_xor(t, 4);
  t = t + __shfl_xor(t, 2);
  float nb = t + __shfl_xor(t, 1);
  float x = nb + __shfl_xor(nb, 16);
  float norm2 = x + __shfl_xor(x, 32);
  const float n = fmaxf(sqrtf(norm2), 1e-12f);

  float* er = e32 + (size_t)row * DD;
  unsigned short* hr = Ehi + (size_t)row * DD;
  unsigned short* lr = Elo + (size_t)row * DD;
#pragma unroll
  for (int m = 0; m < 8; ++m) {
    int k = m * 64 + lane;
    float e = h_elem(fr, W1, W2, k) / n;
    er[k] = e;
    unsigned short hb = f2bf_rne(e);
    hr[k] = hb;
    lr[k] = f2bf_rne(e - bf2f(hb));
  }
}

// ---------------------------------------------------------------------------
// Kernel B: merged 3-term bf16 MFMA sim, upper-triangle 128x128 tiles.
// 2-phase K-loop (BK=32): STAGE(next buf) -> frag reads + 48 MFMAs (cur buf)
// -> ONE __syncthreads (drains next-buf loads after MFMA covered latency).
// Linear LDS tiles AH|AL|BH|BL (8KB each) x 2 buffers.
// Epilogue: round-up bf16 tile write into per-row scratch halves + per-row
// tile-max TM + (bx>by) transposed mirror tile via LDS strips + transposed TM.
// ---------------------------------------------------------------------------
#define OFS_AL 4096   // short offsets into a buffer
#define OFS_BH 8192
#define OFS_BL 12288

#define STAGE(BUF, KK)                        \
  do {                                        \
    char* Ld = L0 + ((BUF) << 15);            \
    gl16(Ehi + rA + (KK), Ld);                \
    gl16(Ehi + rA + H + (KK), Ld + 4096);     \
    gl16(Elo + rA + (KK), Ld + 8192);         \
    gl16(Elo + rA + H + (KK), Ld + 12288);    \
    gl16(Ehi + rB + (KK), Ld + 16384);        \
    gl16(Ehi + rB + H + (KK), Ld + 20480);    \
    gl16(Elo + rB + (KK), Ld + 24576);        \
    gl16(Elo + rB + H + (KK), Ld + 28672);    \
  } while (0)

__global__ __launch_bounds__(256) void sim_mfma(
    const unsigned short* __restrict__ Ehi,
    const unsigned short* __restrict__ Elo, float* __restrict__ C,
    float* __restrict__ TM) {
  // triangular decode: 2080 blocks -> (bx, by) with bx >= by
  int rem = blockIdx.x, by = 0;
  while (rem >= 64 - by) { rem -= 64 - by; ++by; }
  const int bx = by + rem;

  __shared__ __align__(16) char smem[65536];  // 2 x 32KB ping-pong; epi alias
  unsigned short* S = (unsigned short*)smem;
  char* Sc = smem;
  float(*Tt)[133] = (float(*)[133])smem;  // epilogue alias ([64][133] = 34048B)
  __shared__ float rmx[128][2];
  __shared__ float cmx[128][2];

  const int t = threadIdx.x;
  const int lane = t & 63, w = t >> 6;
  const int wr = w >> 1, wc = w & 1;
  const int quad = lane >> 4, l16 = lane & 15;
  const int i0 = by * 128, j0 = bx * 128;

  f32x4 acc[4][4];
#pragma unroll
  for (int a = 0; a < 4; ++a)
#pragma unroll
    for (int b = 0; b < 4; ++b) acc[a][b] = (f32x4){0.f, 0.f, 0.f, 0.f};

  // staging: thread t writes LDS bytes [t*16, t*16+16) of each 4KB tensor-half
  // == row (t>>2), chunk (t&3) of a linear [128][32-short] tile.
  const size_t rA = (size_t)(i0 + (t >> 2)) * DD + (t & 3) * 8;
  const size_t rB = (size_t)(j0 + (t >> 2)) * DD + (t & 3) * 8;
  const size_t H = (size_t)64 * DD;
  char* L0 = Sc + (w << 10);  // wave-uniform LDS base

  STAGE(0, 0);
  __syncthreads();

  int cur = 0;
  for (int kk = 0; kk < DD; kk += 32) {
    if (kk + 32 < DD) STAGE(cur ^ 1, kk + 32);  // issue next tile's loads

    const unsigned short* Sb = S + (cur << 14);  // cur*16384 shorts
    short8 ah[4], al[4], bh[4];
#pragma unroll
    for (int mt = 0; mt < 4; ++mt) {
      int rr = (wr * 64 + mt * 16 + l16) * 32 + quad * 8;
      ah[mt] = *(const short8*)&Sb[rr];
      al[mt] = *(const short8*)&Sb[OFS_AL + rr];
    }
#pragma unroll
    for (int nt = 0; nt < 4; ++nt)
      bh[nt] = *(const short8*)&Sb[OFS_BH + (wc * 64 + nt * 16 + l16) * 32 + quad * 8];
#pragma unroll
    for (int mt = 0; mt < 4; ++mt)
#pragma unroll
      for (int nt = 0; nt < 4; ++nt)
        acc[mt][nt] = __builtin_amdgcn_mfma_f32_16x16x32_bf16(ah[mt], bh[nt], acc[mt][nt], 0, 0, 0);
#pragma unroll
    for (int mt = 0; mt < 4; ++mt)
#pragma unroll
      for (int nt = 0; nt < 4; ++nt)
        acc[mt][nt] = __builtin_amdgcn_mfma_f32_16x16x32_bf16(al[mt], bh[nt], acc[mt][nt], 0, 0, 0);
    short8 bl[4];
#pragma unroll
    for (int nt = 0; nt < 4; ++nt)
      bl[nt] = *(const short8*)&Sb[OFS_BL + (wc * 64 + nt * 16 + l16) * 32 + quad * 8];
#pragma unroll
    for (int mt = 0; mt < 4; ++mt)
#pragma unroll
      for (int nt = 0; nt < 4; ++nt)
        acc[mt][nt] = __builtin_amdgcn_mfma_f32_16x16x32_bf16(ah[mt], bl[nt], acc[mt][nt], 0, 0, 0);

    __syncthreads();  // drains next-buf loads + all waves done reading cur
    cur ^= 1;
  }

  // --- normal tile write: round-up bf16 into per-row scratch ---
#pragma unroll
  for (int mt = 0; mt < 4; ++mt)
#pragma unroll
    for (int r = 0; r < 4; ++r) {
      int row = i0 + wr * 64 + mt * 16 + quad * 4 + r;
      unsigned short* Br = bfrow(C, row) + j0 + wc * 64;
#pragma unroll
      for (int nt = 0; nt < 4; ++nt) Br[nt * 16 + l16] = f2bf_ru(acc[mt][nt][r]);
    }

  // --- per-row tile-max (rows of this tile) ---
#pragma unroll
  for (int mt = 0; mt < 4; ++mt)
#pragma unroll
    for (int r = 0; r < 4; ++r) {
      float m = fmaxf(fmaxf(acc[mt][0][r], acc[mt][1][r]),
                      fmaxf(acc[mt][2][r], acc[mt][3][r]));
      m = fmaxf(m, __shfl_xor(m, 1));
      m = fmaxf(m, __shfl_xor(m, 2));
      m = fmaxf(m, __shfl_xor(m, 4));
      m = fmaxf(m, __shfl_xor(m, 8));
      if (l16 == 0) rmx[wr * 64 + mt * 16 + quad * 4 + r][wc] = m;
    }
  // --- per-col tile-max (rows of the mirrored tile), only if off-diagonal ---
  if (bx > by) {
#pragma unroll
    for (int nt = 0; nt < 4; ++nt) {
      float c = -FLT_MAX;
#pragma unroll
      for (int mt = 0; mt < 4; ++mt)
#pragma unroll
        for (int r = 0; r < 4; ++r) c = fmaxf(c, acc[mt][nt][r]);
      c = fmaxf(c, __shfl_xor(c, 16));
      c = fmaxf(c, __shfl_xor(c, 32));
      if (quad == 0) cmx[wc * 64 + nt * 16 + l16][wr] = c;
    }
  }
  __syncthreads();
  if (t < 128) TM[(size_t)(i0 + t) * 64 + bx] = fmaxf(rmx[t][0], rmx[t][1]);
  if (bx > by) {
    if (t < 128) TM[(size_t)(j0 + t) * 64 + by] = fmaxf(cmx[t][0], cmx[t][1]);
    // --- transposed mirror write via LDS strips (Tt aliases S), bf16-RU out ---
    for (int s = 0; s < 2; ++s) {
      __syncthreads();
      if (wc == s) {
#pragma unroll
        for (int mt = 0; mt < 4; ++mt)
#pragma unroll
          for (int nt = 0; nt < 4; ++nt)
#pragma unroll
            for (int r = 0; r < 4; ++r)
              Tt[nt * 16 + l16][wr * 64 + mt * 16 + quad * 4 + r] = acc[mt][nt][r];
      }
      __syncthreads();
#pragma unroll
      for (int q = 0; q < 8; ++q) {
        int fi = q * 256 + t;
        int rr = fi >> 5;
        int cc4 = (fi & 31) * 4;
        ushort4 v;
        v.x = f2bf_ru(Tt[rr][cc4]);
        v.y = f2bf_ru(Tt[rr][cc4 + 1]);
        v.z = f2bf_ru(Tt[rr][cc4 + 2]);
        v.w = f2bf_ru(Tt[rr][cc4 + 3]);
        *(ushort4*)(bfrow(C, j0 + s * 64 + rr) + i0 + cc4) = v;
      }
    }
  }
}

// ---------------------------------------------------------------------------
// Kernel C1: collect. One WAVE per row. T = 31st largest tile-max via O(64)
// rank-select. Single pass over the bf16-RU row scratch collects cands
// >= T - 2*DELTA (sound: stored >= approx) AND zero-fills the row's first
// 16KB (free stores in a latency-bound kernel); exact fmaf chains re-rank;
// emit KV[row][31] = (idx, relu(exact)). Overflow -> flag (cleanup rewrites).
// ---------------------------------------------------------------------------
__global__ __launch_bounds__(256) void topk_collect(
    float* __restrict__ C, const float* __restrict__ e32,
    const float* __restrict__ TM, int* __restrict__ flags,
    int2* __restrict__ KV) {
  const int w = threadIdx.x >> 6;
  const int lane = threadIdx.x & 63;
  const int row = blockIdx.x * 4 + w;

  __shared__ float er[4][DD];
  __shared__ int cidx[4][CAPW];
  __shared__ float cval[4][CAPW];
  __shared__ int wcnt[4];

  {
    const float4* e4 = (const float4*)(e32 + (size_t)row * DD);
    float4* er4 = (float4*)er[w];
    er4[lane] = e4[lane];
    er4[64 + lane] = e4[64 + lane];
  }
  if (lane == 0) wcnt[w] = 0;

  // T = 31st largest of 64 tile maxima: rank-select with independent shuffles.
  float mv = TM[(size_t)row * 64 + lane];
  unsigned key = ordmap(mv);
  int rank = 0;
#pragma unroll
  for (int off = 1; off < 64; ++off) {
    int ol = (lane + off) & 63;
    unsigned ok = __shfl(key, ol);
    rank += (ok > key || (ok == key && ol < lane)) ? 1 : 0;
  }
  unsigned long long bmsk = __ballot(rank == TOPK - 1);
  float T = __shfl(mv, __ffsll((unsigned long long)bmsk) - 1);

  // single row pass over bf16-RU scratch: collect candidates + zero 1st half
  const float Tc = T - 2.0f * DELTA;
  const unsigned short* Brow =
      (const unsigned short*)C + (size_t)row * (2 * NN) + NN;
  const uint4* Br4 = (const uint4*)Brow;
  float4* Zw4 = (float4*)(C + (size_t)row * NN);  // first 16KB = 1024 float4
  const float4 z4 = make_float4(0.f, 0.f, 0.f, 0.f);
  for (int it = 0; it < NN / 512; ++it) {
    uint4 v = Br4[it * 64 + lane];
    Zw4[it * 64 + lane] = z4;
    int j = (it * 64 + lane) * 8;
    unsigned wv[4] = {v.x, v.y, v.z, v.w};
#pragma unroll
    for (int c = 0; c < 4; ++c) {
      float f0 = __uint_as_float(wv[c] << 16);
      float f1 = __uint_as_float(wv[c] & 0xffff0000u);
      if (f0 >= Tc) { int p = atomicAdd(&wcnt[w], 1); if (p < CAPW) cidx[w][p] = j + 2 * c; }
      if (f1 >= Tc) { int p = atomicAdd(&wcnt[w], 1); if (p < CAPW) cidx[w][p] = j + 2 * c + 1; }
    }
  }
  const int cnt = wcnt[w];

  if (cnt > CAPW) {
    if (lane == 0) flags[row] = 1;
    return;
  }

  // exact sequential-k fmaf chains (bit-identical to the verified chain)
  for (int c = lane; c < cnt; c += 64) {
    const float4* ej4 = (const float4*)(e32 + (size_t)cidx[w][c] * DD);
    float a = 0.f;
    for (int k4 = 0; k4 < DD / 4; ++k4) {
      float4 vv = ej4[k4];
      const float* e = &er[w][k4 * 4];
      a = fmaf(e[0], vv.x, a);
      a = fmaf(e[1], vv.y, a);
      a = fmaf(e[2], vv.z, a);
      a = fmaf(e[3], vv.w, a);
    }
    cval[w][c] = a;
  }

  // stable top-31 by (exact desc, idx asc) -> KV pairs
  for (int c = lane; c < cnt; c += 64) {
    float v = cval[w][c];
    int idx = cidx[w][c];
    int rnk = 0;
    for (int c2 = 0; c2 < cnt; ++c2) {
      float v2 = cval[w][c2];
      if (v2 > v || (v2 == v && cidx[w][c2] < idx)) ++rnk;
    }
    if (rnk < TOPK)
      KV[(size_t)row * TOPK + rnk] =
          make_int2(idx, __float_as_int(fmaxf(v, 0.0f)));
  }
}

// ---------------------------------------------------------------------------
// Kernel C2: writer. One block per row: zero the SECOND 16KB (bf16 scratch
// half; first half was zeroed by collect), barrier (drains stores), then
// lanes 0..30 scatter the 31 values anywhere in the row. Pure write-BW bound.
// ---------------------------------------------------------------------------
__global__ __launch_bounds__(256) void write_kernel(float* __restrict__ C,
                                                    const int2* __restrict__ KV) {
  const int row = blockIdx.x;
  const int t = threadIdx.x;
  int j = 0;
  float v = 0.f;
  if (t < TOPK) {
    int2 p = KV[(size_t)row * TOPK + t];
    j = p.x & (NN - 1);
    v = __int_as_float(p.y);
  }
  const float4 z = make_float4(0.f, 0.f, 0.f, 0.f);
  float4* Cw4 = (float4*)(C + (size_t)row * NN + NN / 2);  // second 16KB
#pragma unroll
  for (int i = 0; i < NN / 8 / 256; ++i) Cw4[i * 256 + t] = z;
  __syncthreads();  // vmcnt(0) drain: zeros committed before value stores
  if (t < TOPK) C[(size_t)row * NN + j] = v;
}

// ---------------------------------------------------------------------------
// Kernel D: exact cleanup for flagged rows (statistically never executes).
// ---------------------------------------------------------------------------
__global__ __launch_bounds__(256) void cleanup_kernel(
    float* __restrict__ C, const float* __restrict__ e32,
    const int* __restrict__ flags) {
  const int row = blockIdx.x;
  if (flags[row] == 0) return;
  const int tid = threadIdx.x;
  const int lane = tid & 63, wid = tid >> 6;

  __shared__ float sv[NN];
  __shared__ float er[DD];
  __shared__ unsigned long long wred[4];
  __shared__ int kidx[TOPK];
  __shared__ float kval[TOPK];

  {
    const float4* e4 = (const float4*)(e32 + (size_t)row * DD);
    if (tid < DD / 4) ((float4*)er)[tid] = e4[tid];
  }
  __syncthreads();

  for (int m = 0; m < NN / 256; ++m) {
    int j = m * 256 + tid;
    const float* ej = e32 + (size_t)j * DD;
    float a = 0.f;
    for (int k = 0; k < DD; k += 4) {
      float4 v = *(const float4*)&ej[k];
      a = fmaf(er[k], v.x, a);
      a = fmaf(er[k + 1], v.y, a);
      a = fmaf(er[k + 2], v.z, a);
      a = fmaf(er[k + 3], v.w, a);
    }
    sv[j] = a;
  }
  __syncthreads();

  for (int it = 0; it < TOPK; ++it) {
    float bv = -FLT_MAX;
    int bi = 0;
    for (int j = tid; j < NN; j += 256) {
      float v = sv[j];
      if (v > bv) { bv = v; bi = j; }
    }
    unsigned long long key =
        ((unsigned long long)ordmap(bv) << 32) | (unsigned)(NN - 1 - bi);
#pragma unroll
    for (int off = 32; off; off >>= 1) {
      unsigned long long o = __shfl_xor(key, off);
      if (o > key) key = o;
    }
    if (lane == 0) wred[wid] = key;
    __syncthreads();
    if (tid == 0) {
      unsigned long long k0 = wred[0];
      if (wred[1] > k0) k0 = wred[1];
      if (wred[2] > k0) k0 = wred[2];
      if (wred[3] > k0) k0 = wred[3];
      int idx = (NN - 1) - (int)(k0 & 0xFFFFFFFFu);
      kidx[it] = idx;
      kval[it] = sv[idx];
      sv[idx] = -FLT_MAX;
    }
    __syncthreads();
  }

  float4 z4 = make_float4(0.f, 0.f, 0.f, 0.f);
  float4* sv4 = (float4*)sv;
  for (int i = tid; i < NN / 4; i += 256) sv4[i] = z4;
  __syncthreads();
  if (tid < TOPK) sv[kidx[tid]] = fmaxf(kval[tid], 0.0f);
  __syncthreads();
  float4* Cw4 = (float4*)(C + (size_t)row * NN);
  for (int i = tid; i < NN / 4; i += 256) Cw4[i] = sv4[i];
}

// ---------------------------------------------------------------------------
extern "C" void kernel_launch(void* const* d_in, const int* in_sizes, int n_in,
                              void* d_out, int out_size, void* d_ws,
                              size_t ws_size, hipStream_t stream) {
  const float* f = (const float*)d_in[0];
  const float* W1 = (const float*)d_in[1];
  const float* W2 = (const float*)d_in[2];
  float* out = (float*)d_out;
  char* ws = (char*)d_ws;
  float* e32 = (float*)ws;                                     // 16 MiB
  unsigned short* Ehi = (unsigned short*)(ws + (size_t)NN * DD * 4);   // 8 MiB
  unsigned short* Elo = (unsigned short*)(ws + (size_t)NN * DD * 6);   // 8 MiB
  float* TM = (float*)(ws + (size_t)NN * DD * 8);              // 2 MiB
  int* flags = (int*)(ws + (size_t)NN * DD * 8 + (size_t)NN * 64 * 4);  // 32 KB
  int2* KV = (int2*)(ws + (size_t)NN * DD * 8 + (size_t)NN * 64 * 4 +
                     (size_t)NN * 8);  // ~2 MiB (8192*31*8 B)

  emb_kernel<<<NN / 4, 256, 0, stream>>>(f, W1, W2, e32, Ehi, Elo, flags);
  sim_mfma<<<2080, 256, 0, stream>>>(Ehi, Elo, out, TM);
  topk_collect<<<NN / 4, 256, 0, stream>>>(out, e32, TM, flags, KV);
  write_kernel<<<NN, 256, 0, stream>>>(out, KV);
  cleanup_kernel<<<NN, 256, 0, stream>>>(out, e32, flags);
}